// Round 10
// baseline (64.626 us; speedup 1.0000x reference)
//
#include <hip/hip_runtime.h>
#include <hip/hip_bf16.h>

typedef __attribute__((ext_vector_type(4))) float f32x4;
typedef __attribute__((ext_vector_type(8))) short short8;
typedef __attribute__((ext_vector_type(8))) unsigned short ushort8;
typedef __attribute__((ext_vector_type(4))) unsigned short ushort4v;

#define M_ROWS 16384
#define KDIM 512
#define UDIM 512
#define IN_STRIDE 1024
#define NPH 8             // 8 phases x 64 k

__device__ __forceinline__ unsigned short f2bf(float f) {
    union { float f; unsigned u; } v; v.f = f;
    unsigned r = v.u + 0x7FFFu + ((v.u >> 16) & 1u);  // RTNE
    return (unsigned short)(r >> 16);
}

// packed RNE f32x2 -> bf16x2 (compiler emits v_cvt_pk_bf16_f32)
__device__ __forceinline__ unsigned cvt2(float a, float b) {
    __hip_bfloat162 h = __float22bfloat162_rn(float2{a, b});
    union { __hip_bfloat162 h; unsigned u; } c; c.h = h; return c.u;
}

// global_load_lds, width 16 (literal required)
#define GLD16(g, l)                                                            \
    __builtin_amdgcn_global_load_lds(                                          \
        (const __attribute__((address_space(1))) void*)(g),                    \
        (__attribute__((address_space(3))) void*)(l), 16, 0, 0)

// ---------------------------------------------------------------------------
// weights pack: Wp[ub 8][ph 8][slot 1024] x 16B. slot S: jj=S>>3, phys piece
// P=S&7, logical piece L = P ^ (jj&7)  (G4 XOR swizzle baked), content =
// w[ph*64 + L*8 .. +8][u(jj)] as bf16x8. gru_gemm streams it linearly.
// ---------------------------------------------------------------------------
__global__ __launch_bounds__(256) void pack_w(
    const float* __restrict__ w_z,
    const float* __restrict__ w_h,
    unsigned short* __restrict__ Wp)
{
    int g  = blockIdx.x * 256 + threadIdx.x;   // [0, 65536)
    int S  = g & 1023;
    int ph = (g >> 10) & 7;
    int ub = g >> 13;
    int jj = S >> 3;
    int P  = S & 7;
    int L  = P ^ (jj & 7);
    int k0 = ph * 64 + L * 8;
    const float* w = ((jj >> 5) & 1) ? w_h : w_z;
    int u = ub * 64 + ((jj >> 6) << 5) + (jj & 31);
    ushort8 v;
#pragma unroll
    for (int i = 0; i < 8; ++i)
        v[i] = f2bf(w[(size_t)(k0 + i) * UDIM + u]);
    *reinterpret_cast<ushort8*>(Wp + (size_t)g * 8) = v;
}

// ---------------------------------------------------------------------------
// Fused GEMM: 128(M) x 128(jj) tile, 2-K-step phases (BK=64/phase, 8 phases),
// 4 waves. A: x fp32 -> regs (issue at phase start) -> cvt_pk -> swizzled
// ds_write into [128][64]u16 phase-buf (ring-2). B: packed Wp via
// global_load_lds into ring-3 phase-bufs, lookahead 2 phases, counted
// vmcnt(4) across the fenced barrier (never drains mid-loop). Both tiles use
// piece-XOR swizzle P = L ^ (row&7) -> conflict-free ds_read_b128.
// ---------------------------------------------------------------------------
__global__ __launch_bounds__(256, 2) void gru_gemm(
    const float* __restrict__ x,            // (16384, 1024), cols [0,512) used
    const unsigned short* __restrict__ Wp,  // packed weights
    const float* __restrict__ b_z,
    const float* __restrict__ b_h,
    float* __restrict__ out)
{
    __shared__ __align__(16) unsigned char smem[81920];
    unsigned short* shA = (unsigned short*)smem;             // 2 bufs x 8192 u16
    unsigned short* shB = (unsigned short*)(smem + 32768);   // 3 bufs x 8192 u16

    const int tid  = threadIdx.x;
    const int lane = tid & 63;
    const int wid  = tid >> 6;
    const int wm   = wid >> 1;
    const int wn   = wid & 1;

    // XCD-aware swizzle: the 8 u-blocks of a row-panel land on one XCD
    const int d  = blockIdx.x;               // [0,1024)
    const int bx = (d >> 3) & 7;             // u-block
    const int by = (d & 7) * 16 + (d >> 6);  // row-panel
    const int u0   = bx * 64;
    const int brow = by * 128;

    // ---- A staging: thread owns row rrow, k-step rs within the phase ----
    const int rrow = tid & 127;
    const int rs   = tid >> 7;               // 0 or 1
    const float* gAr = x + (size_t)(brow + rrow) * IN_STRIDE + rs * 32;
    const int awbase = rrow * 64;             // u16 row offset
    const int rx7    = rrow & 7;

    const unsigned short* bp = Wp + (size_t)bx * 65536;

    f32x4 acc[4][4];
#pragma unroll
    for (int m = 0; m < 4; ++m)
#pragma unroll
        for (int n = 0; n < 4; ++n)
            acc[m][n] = (f32x4){0.f, 0.f, 0.f, 0.f};

    f32x4 rA[8];   // one phase of A per thread: 32 floats (issued & consumed per phase)

#define ISSUE_A(ph)                                                            \
    {                                                                          \
        _Pragma("unroll")                                                      \
        for (int i = 0; i < 8; ++i)                                            \
            rA[i] = *reinterpret_cast<const f32x4*>(gAr + (ph) * 64 + i * 4);  \
    }

#define ISSUE_B(ph, b)                                                         \
    {                                                                          \
        _Pragma("unroll")                                                      \
        for (int i = 0; i < 4; ++i)                                            \
            GLD16(bp + (size_t)(ph) * 8192 + (wid * 256 + i * 64 + lane) * 8,  \
                  shB + (b) * 8192 + wid * 2048 + i * 512);                    \
    }

#define CVT_WRITE_A(ph)                                                        \
    {                                                                          \
        const int ab_ = ((ph) & 1) * 8192;                                     \
        _Pragma("unroll")                                                      \
        for (int j = 0; j < 4; ++j) {                                          \
            union { unsigned u[4]; ushort8 v; } c;                             \
            c.u[0] = cvt2(rA[2 * j][0], rA[2 * j][1]);                         \
            c.u[1] = cvt2(rA[2 * j][2], rA[2 * j][3]);                         \
            c.u[2] = cvt2(rA[2 * j + 1][0], rA[2 * j + 1][1]);                 \
            c.u[3] = cvt2(rA[2 * j + 1][2], rA[2 * j + 1][3]);                 \
            int piece = (rs * 4 + j) ^ rx7;                                    \
            *reinterpret_cast<ushort8*>(&shA[ab_ + awbase + piece * 8]) = c.v; \
        }                                                                      \
    }

    // fragment read addressing: piece = (s*4 + ks) ^ (fr&7) (lane-constant)
    const int fr  = lane & 15;
    const int ks  = lane >> 4;
    const int pc0 = (ks)     ^ (fr & 7);
    const int pc1 = (4 + ks) ^ (fr & 7);
    int arow[4], brw[4];
#pragma unroll
    for (int m = 0; m < 4; ++m)
        arow[m] = (wm * 64 + m * 16 + fr) * 64;
#pragma unroll
    for (int n = 0; n < 4; ++n)
        brw[n] = (wn * 64 + n * 16 + fr) * 64;

    // prologue: A(0) regs + B(0),B(1) in flight; land A(0)+B(0); B(1) flies
    ISSUE_A(0);
    ISSUE_B(0, 0);
    ISSUE_B(1, 1);
    asm volatile("s_waitcnt vmcnt(4)" ::: "memory");
    CVT_WRITE_A(0);
    asm volatile("s_waitcnt lgkmcnt(0)" ::: "memory");
    asm volatile("s_barrier" ::: "memory");

#pragma unroll
    for (int p = 0; p < NPH; ++p) {
        if (p + 1 < NPH) ISSUE_A(p + 1);            // A issued first,
        if (p + 2 < NPH) ISSUE_B(p + 2, (p + 2) % 3); // B newest -> vmcnt(4)
        const int ab = (p & 1) * 8192;
        const int bb = (p % 3) * 8192;
        short8 af0[4], af1[4], bf0[4], bf1[4];
#pragma unroll
        for (int m = 0; m < 4; ++m) {
            af0[m] = *reinterpret_cast<const short8*>(&shA[ab + arow[m] + pc0 * 8]);
            af1[m] = *reinterpret_cast<const short8*>(&shA[ab + arow[m] + pc1 * 8]);
        }
#pragma unroll
        for (int n = 0; n < 4; ++n) {
            bf0[n] = *reinterpret_cast<const short8*>(&shB[bb + brw[n] + pc0 * 8]);
            bf1[n] = *reinterpret_cast<const short8*>(&shB[bb + brw[n] + pc1 * 8]);
        }
#pragma unroll
        for (int m = 0; m < 4; ++m)
#pragma unroll
            for (int n = 0; n < 4; ++n) {
                acc[m][n] = __builtin_amdgcn_mfma_f32_16x16x32_bf16(af0[m], bf0[n], acc[m][n], 0, 0, 0);
                acc[m][n] = __builtin_amdgcn_mfma_f32_16x16x32_bf16(af1[m], bf1[n], acc[m][n], 0, 0, 0);
            }
        if (p + 1 < NPH) {
            if (p + 2 < NPH) {
                // A(p+1)+B(p+1) landed; B(p+2) (4 loads) stays in flight
                asm volatile("s_waitcnt vmcnt(4)" ::: "memory");
            } else {
                asm volatile("s_waitcnt vmcnt(0)" ::: "memory");
            }
            CVT_WRITE_A(p + 1);   // buf (p+1)&1: last read at phase p-1
            asm volatile("s_waitcnt lgkmcnt(0)" ::: "memory");
            asm volatile("s_barrier" ::: "memory");
        }
    }

    __syncthreads();   // full fence before LDS reuse

    // ---- epilogue: s = sigmoid(z+bz)*tanh(h+bh) in regs -> LDS plane ----
    float* plane = (float*)smem;   // [128][68] f32 = 34816 B, fits
    const int fq = ks;
#pragma unroll
    for (int p = 0; p < 2; ++p) {
        int ucol = wn * 32 + p * 16 + fr;
        float bz = b_z[u0 + ucol];
        float bh = b_h[u0 + ucol];
#pragma unroll
        for (int m = 0; m < 4; ++m) {
            int row0 = wm * 64 + m * 16 + fq * 4;
            f32x4 az = acc[m][p];
            f32x4 ah = acc[m][p + 2];
#pragma unroll
            for (int j = 0; j < 4; ++j) {
                float zt = 1.f / (1.f + __expf(-(az[j] + bz)));
                float e  = __expf(2.f * (ah[j] + bh));
                float s  = zt * (1.f - 2.f / (e + 1.f));
                plane[(row0 + j) * 68 + ucol] = s;
            }
        }
    }
    __syncthreads();

    // ---- transposed float4 stores: 256B contiguous per quarter-wave ----
    float* fwd = out;
    float* seq = out + (size_t)M_ROWS * 1024;
    const f32x4 z4 = (f32x4){0.f, 0.f, 0.f, 0.f};
    const int c4 = (tid & 15) * 4;
#pragma unroll
    for (int it = 0; it < 8; ++it) {
        int row = it * 16 + (tid >> 4);
        f32x4 v = *reinterpret_cast<const f32x4*>(&plane[row * 68 + c4]);
        size_t grow = (size_t)(brow + row);
        *reinterpret_cast<f32x4*>(&fwd[grow * 1024 + u0 + c4])       = v;
        *reinterpret_cast<f32x4*>(&fwd[grow * 1024 + 512 + u0 + c4]) = z4;
        *reinterpret_cast<f32x4*>(&seq[grow * 512 + u0 + c4])        = v;
    }
#undef ISSUE_A
#undef ISSUE_B
#undef CVT_WRITE_A
}

// ---------------------------------------------------------------------------
// Legacy fallback (round-1 kernel, needs no workspace) if ws is too small
// ---------------------------------------------------------------------------
#define LDSS 40
#define NSTEP 16
__global__ __launch_bounds__(256) void gru_fused_legacy(
    const float* __restrict__ inp, const float* __restrict__ w_z,
    const float* __restrict__ b_z, const float* __restrict__ w_h,
    const float* __restrict__ b_h, float* __restrict__ out)
{
    __shared__ __align__(16) unsigned short Asl[2][128][LDSS];
    __shared__ __align__(16) unsigned short Bsl[2][128][LDSS];
    const int tid = threadIdx.x, lane = tid & 63, wid = tid >> 6;
    const int wm = wid >> 1, wn = wid & 1;
    const int u0 = blockIdx.x * 64, brow = blockIdx.y * 128;
    f32x4 acc[4][4];
#pragma unroll
    for (int m = 0; m < 4; ++m)
#pragma unroll
        for (int n = 0; n < 4; ++n) acc[m][n] = (f32x4){0.f,0.f,0.f,0.f};
    f32x4 rA[4], rB[4];
#define STAGE_LOAD(kt) { const int k0_=(kt)*32; \
    _Pragma("unroll") for (int it=0; it<4; ++it){ int idx=tid+256*it; int r=idx>>3,c=(idx&7)<<2; \
        rA[it]=*reinterpret_cast<const f32x4*>(inp+(size_t)(brow+r)*IN_STRIDE+k0_+c);} \
    _Pragma("unroll") for (int it=0; it<4; ++it){ int idx=tid+256*it; int jj=idx&127; int k4=(idx>>7)<<2; \
        const float* w_=((jj>>5)&1)?w_h:w_z; int u_=u0+((jj>>6)<<5)+(jj&31); \
        const float* p_=w_+(size_t)(k0_+k4)*UDIM+u_; \
        rB[it][0]=p_[0]; rB[it][1]=p_[UDIM]; rB[it][2]=p_[2*UDIM]; rB[it][3]=p_[3*UDIM];} }
#define STAGE_WRITE(bufi) { \
    _Pragma("unroll") for (int it=0; it<4; ++it){ int idx=tid+256*it; int r=idx>>3,c=(idx&7)<<2; ushort4v v; \
        v[0]=f2bf(rA[it][0]); v[1]=f2bf(rA[it][1]); v[2]=f2bf(rA[it][2]); v[3]=f2bf(rA[it][3]); \
        *reinterpret_cast<ushort4v*>(&Asl[bufi][r][c])=v;} \
    _Pragma("unroll") for (int it=0; it<4; ++it){ int idx=tid+256*it; int jj=idx&127; int k4=(idx>>7)<<2; ushort4v v; \
        v[0]=f2bf(rB[it][0]); v[1]=f2bf(rB[it][1]); v[2]=f2bf(rB[it][2]); v[3]=f2bf(rB[it][3]); \
        *reinterpret_cast<ushort4v*>(&Bsl[bufi][jj][k4])=v;} }
    STAGE_LOAD(0); STAGE_WRITE(0);
    const int fr = lane & 15, koff = (lane >> 4) << 3;
    for (int kt = 0; kt < NSTEP; ++kt) {
        if (kt + 1 < NSTEP) STAGE_LOAD(kt + 1);
        __syncthreads();
        const int buf = kt & 1;
        short8 af[4], bfr[4];
#pragma unroll
        for (int m = 0; m < 4; ++m) af[m] = *reinterpret_cast<const short8*>(&Asl[buf][wm*64+m*16+fr][koff]);
#pragma unroll
        for (int n = 0; n < 4; ++n) bfr[n] = *reinterpret_cast<const short8*>(&Bsl[buf][wn*64+n*16+fr][koff]);
#pragma unroll
        for (int m = 0; m < 4; ++m)
#pragma unroll
            for (int n = 0; n < 4; ++n)
                acc[m][n] = __builtin_amdgcn_mfma_f32_16x16x32_bf16(af[m], bfr[n], acc[m][n], 0, 0, 0);
        if (kt + 1 < NSTEP) STAGE_WRITE((kt + 1) & 1);
    }
    float* fwd = out; float* seq = out + (size_t)M_ROWS * 1024;
    const int fq = lane >> 4;
#pragma unroll
    for (int p = 0; p < 2; ++p) {
        int u = u0 + wn * 32 + p * 16 + fr;
        float bz = b_z[u], bh = b_h[u];
#pragma unroll
        for (int m = 0; m < 4; ++m) {
            int row0 = brow + wm * 64 + m * 16 + fq * 4;
            f32x4 az = acc[m][p], ah = acc[m][p + 2];
#pragma unroll
            for (int j = 0; j < 4; ++j) {
                float zt = 1.f / (1.f + __expf(-(az[j] + bz)));
                float e  = __expf(2.f * (ah[j] + bh));
                float s  = zt * (1.f - 2.f / (e + 1.f));
                size_t rr = (size_t)(row0 + j);
                fwd[rr * 1024 + u] = s;
                fwd[rr * 1024 + 512 + u] = 0.f;
                seq[rr * 512 + u] = s;
            }
        }
    }
}

extern "C" void kernel_launch(void* const* d_in, const int* in_sizes, int n_in,
                              void* d_out, int out_size, void* d_ws, size_t ws_size,
                              hipStream_t stream) {
    const float* inp = (const float*)d_in[0];
    const float* w_z = (const float*)d_in[2];
    const float* b_z = (const float*)d_in[4];
    const float* w_h = (const float*)d_in[8];
    const float* b_h = (const float*)d_in[10];
    float* out = (float*)d_out;

    const size_t needW = (size_t)8 * 8 * 1024 * 16;   // 1 MiB packed weights
    if (ws_size >= needW) {
        unsigned short* Wp = (unsigned short*)d_ws;
        hipLaunchKernelGGL(pack_w, dim3(256), dim3(256), 0, stream, w_z, w_h, Wp);
        hipLaunchKernelGGL(gru_gemm, dim3(1024), dim3(256), 0, stream,
                           inp, Wp, b_z, b_h, out);
    } else {
        hipLaunchKernelGGL(gru_fused_legacy, dim3(8, 128), dim3(256), 0, stream,
                           inp, w_z, b_z, w_h, b_h, out);
    }
}

// Round 11
// 46.207 us; speedup vs baseline: 1.3986x; 1.3986x over previous
//
#include <hip/hip_runtime.h>
#include <hip/hip_bf16.h>

typedef __attribute__((ext_vector_type(4))) float f32x4;
typedef __attribute__((ext_vector_type(8))) short short8;
typedef __attribute__((ext_vector_type(8))) unsigned short ushort8;
typedef __attribute__((ext_vector_type(4))) unsigned short ushort4v;

#define M_ROWS 16384
#define KDIM 512
#define UDIM 512
#define IN_STRIDE 1024
#define NSTEP 16          // K / 32

__device__ __forceinline__ unsigned short f2bf(float f) {
    union { float f; unsigned u; } v; v.f = f;
    unsigned r = v.u + 0x7FFFu + ((v.u >> 16) & 1u);  // RTNE
    return (unsigned short)(r >> 16);
}

// packed RNE f32x2 -> bf16x2 (compiler emits v_cvt_pk_bf16_f32)
__device__ __forceinline__ unsigned cvt2(float a, float b) {
    __hip_bfloat162 h = __float22bfloat162_rn(float2{a, b});
    union { __hip_bfloat162 h; unsigned u; } c; c.h = h; return c.u;
}

// global_load_lds, width 16 (literal required)
#define GLD16(g, l)                                                            \
    __builtin_amdgcn_global_load_lds(                                          \
        (const __attribute__((address_space(1))) void*)(g),                    \
        (__attribute__((address_space(3))) void*)(l), 16, 0, 0)

// ---------------------------------------------------------------------------
// weights pack: Wp[ub 8][kt 16][s 512] x 16B slots, XOR-swizzle baked into
// the k-slot order so gru_gemm's global_load_lds consumes it linearly.
// ---------------------------------------------------------------------------
__global__ __launch_bounds__(256) void pack_w(
    const float* __restrict__ w_z,
    const float* __restrict__ w_h,
    unsigned short* __restrict__ Wp)
{
    int tid = blockIdx.x * 256 + threadIdx.x;   // [0, 65536)
    int s   = tid & 511;
    int kt  = (tid >> 9) & 15;
    int ub  = tid >> 13;
    int jj  = s >> 2;
    int sl  = (s & 3) ^ ((jj >> 1) & 3);
    int k   = kt * 32 + sl * 8;
    const float* w = ((jj >> 5) & 1) ? w_h : w_z;
    int u = ub * 64 + ((jj >> 6) << 5) + (jj & 31);
    ushort8 v;
#pragma unroll
    for (int i = 0; i < 8; ++i)
        v[i] = f2bf(w[(size_t)(k + i) * UDIM + u]);
    *reinterpret_cast<ushort8*>(Wp + (size_t)tid * 8) = v;
}

// ---------------------------------------------------------------------------
// Fused GEMM (R9 structure, residency 3 -> 4 blocks/CU): 128x128 tile, BK=32,
// 4 waves. A: x fp32 -> regs (depth-2 ring) -> v_cvt_pk_bf16_f32 ->
// ds_write_b128 into bf16 [128][32] tile (2 bufs). B: packed Wp via
// global_load_lds, ring-3. Counted vmcnt(6), asm-fenced barriers, per-wave
// lgkmcnt(0) drain. LDS 40960 B exactly -> 4 blocks = full 160 KiB/CU; grid
// 1024 = 4 x 256 CUs -> all blocks resident, barriers hidden by TLP.
// ---------------------------------------------------------------------------
__global__ __launch_bounds__(256, 4) void gru_gemm(
    const float* __restrict__ x,            // (16384, 1024), cols [0,512) used
    const unsigned short* __restrict__ Wp,  // packed weights
    const float* __restrict__ b_z,
    const float* __restrict__ b_h,
    float* __restrict__ out)
{
    __shared__ __align__(16) unsigned char smem[40960];
    unsigned short* shA = (unsigned short*)smem;            // 2 bufs x 4096 u16
    unsigned short* shB = (unsigned short*)(smem + 16384);  // 3 bufs x 4096 u16

    const int tid  = threadIdx.x;
    const int lane = tid & 63;
    const int wid  = tid >> 6;
    const int wm   = wid >> 1;
    const int wn   = wid & 1;

    // XCD-aware swizzle: the 8 u-blocks of a row-panel land on one XCD
    const int d  = blockIdx.x;               // [0,1024)
    const int bx = (d >> 3) & 7;             // u-block
    const int by = (d & 7) * 16 + (d >> 6);  // row-panel
    const int u0   = bx * 64;
    const int brow = by * 128;

    // ---- A staging: thread owns 2 16B LDS slots; slot s -> row r=s>>2,
    //      piece p=s&3; content = global k-octet q = p ^ ((r>>1)&3) ----
    const int s0a = wid * 128 + lane;
    const int s1a = s0a + 64;
    const int r0 = s0a >> 2, r1 = s1a >> 2;
    const int q0 = (s0a & 3) ^ ((r0 >> 1) & 3);
    const int q1 = (s1a & 3) ^ ((r1 >> 1) & 3);
    const float* gA0 = x + (size_t)(brow + r0) * IN_STRIDE + q0 * 8;
    const float* gA1 = x + (size_t)(brow + r1) * IN_STRIDE + q1 * 8;

    const unsigned short* bp = Wp + (size_t)bx * 65536 + (size_t)s0a * 8;

    f32x4 acc[4][4];
#pragma unroll
    for (int m = 0; m < 4; ++m)
#pragma unroll
        for (int n = 0; n < 4; ++n)
            acc[m][n] = (f32x4){0.f, 0.f, 0.f, 0.f};

    f32x4 rA[2][4];   // A in-flight register ring (static indices under unroll)

#define ISSUE_AREG(t, set)                                                     \
    {                                                                          \
        rA[set][0] = *reinterpret_cast<const f32x4*>(gA0 + (t) * 32);          \
        rA[set][1] = *reinterpret_cast<const f32x4*>(gA0 + (t) * 32 + 4);      \
        rA[set][2] = *reinterpret_cast<const f32x4*>(gA1 + (t) * 32);          \
        rA[set][3] = *reinterpret_cast<const f32x4*>(gA1 + (t) * 32 + 4);      \
    }

#define ISSUE_B(t, b)                                                          \
    {                                                                          \
        GLD16(bp + (size_t)(t) * 4096,       shB + (b) * 4096 + wid * 1024);   \
        GLD16(bp + (size_t)(t) * 4096 + 512, shB + (b) * 4096 + wid * 1024 + 512); \
    }

#define CVT_WRITE_A(set, b)                                                    \
    {                                                                          \
        union { unsigned u[4]; ushort8 v; } c0, c1;                            \
        c0.u[0] = cvt2(rA[set][0][0], rA[set][0][1]);                          \
        c0.u[1] = cvt2(rA[set][0][2], rA[set][0][3]);                          \
        c0.u[2] = cvt2(rA[set][1][0], rA[set][1][1]);                          \
        c0.u[3] = cvt2(rA[set][1][2], rA[set][1][3]);                          \
        c1.u[0] = cvt2(rA[set][2][0], rA[set][2][1]);                          \
        c1.u[1] = cvt2(rA[set][2][2], rA[set][2][3]);                          \
        c1.u[2] = cvt2(rA[set][3][0], rA[set][3][1]);                          \
        c1.u[3] = cvt2(rA[set][3][2], rA[set][3][3]);                          \
        *reinterpret_cast<ushort8*>(&shA[(b) * 4096 + s0a * 8]) = c0.v;        \
        *reinterpret_cast<ushort8*>(&shA[(b) * 4096 + s1a * 8]) = c1.v;        \
    }

    // fragment read offsets (ushort units), xo swizzle (R4-proven, both tiles)
    const int fr = lane & 15;
    const int ks = lane >> 4;
    const int xo = (fr >> 1) & 3;
    int aoff[4], boff[4];
#pragma unroll
    for (int m = 0; m < 4; ++m)
        aoff[m] = (wm * 64 + m * 16 + fr) * 32 + ((ks ^ xo) << 3);
#pragma unroll
    for (int n = 0; n < 4; ++n)
        boff[n] = (wn * 64 + n * 16 + fr) * 32 + ((ks ^ xo) << 3);

    // prologue: stages 0,1 in flight; land 0, write A(0), fenced barrier
    ISSUE_AREG(0, 0); ISSUE_B(0, 0);
    ISSUE_AREG(1, 1); ISSUE_B(1, 1);
    asm volatile("s_waitcnt vmcnt(6)" ::: "memory");   // A(0) regs + B(0) LDS
    CVT_WRITE_A(0, 0);
    asm volatile("s_waitcnt lgkmcnt(0)" ::: "memory");
    asm volatile("s_barrier" ::: "memory");

#pragma unroll
    for (int t = 0; t < NSTEP; ++t) {
        if (t + 2 < NSTEP) {
            ISSUE_AREG(t + 2, t & 1);        // set t&1 consumed at step t-1
            ISSUE_B(t + 2, (t + 2) % 3);     // slot read at t-1, waves past it
        }
        const int ba = t & 1, bb = t % 3;
        short8 af[4], bfrag[4];
#pragma unroll
        for (int m = 0; m < 4; ++m)
            af[m] = *reinterpret_cast<const short8*>(&shA[ba * 4096 + aoff[m]]);
#pragma unroll
        for (int n = 0; n < 4; ++n)
            bfrag[n] = *reinterpret_cast<const short8*>(&shB[bb * 4096 + boff[n]]);
#pragma unroll
        for (int m = 0; m < 4; ++m)
#pragma unroll
            for (int n = 0; n < 4; ++n)
                acc[m][n] = __builtin_amdgcn_mfma_f32_16x16x32_bf16(af[m], bfrag[n], acc[m][n], 0, 0, 0);
        if (t + 1 < NSTEP) {
            if (t + 2 < NSTEP) {
                // A(t+1) regs + B(t+1) LDS landed; stage t+2's 6 ops in flight
                asm volatile("s_waitcnt vmcnt(6)" ::: "memory");
            } else {
                asm volatile("s_waitcnt vmcnt(0)" ::: "memory");
            }
            CVT_WRITE_A((t + 1) & 1, (t + 1) & 1);  // buffer consumed at t-1
            // my frag reads + A-writes complete before crossing the barrier
            asm volatile("s_waitcnt lgkmcnt(0)" ::: "memory");
            asm volatile("s_barrier" ::: "memory");
        }
    }

    __syncthreads();   // full fence before LDS reuse (drains lgkm+vm per wave)

    // ---- epilogue: s = sigmoid(z+bz)*tanh(h+bh) in regs -> LDS plane ----
    float* plane = (float*)smem;   // [128][68] f32 = 34816 B, fits in 40960
    const int fq = lane >> 4;
#pragma unroll
    for (int p = 0; p < 2; ++p) {
        int ucol = wn * 32 + p * 16 + fr;
        float bz = b_z[u0 + ucol];
        float bh = b_h[u0 + ucol];
#pragma unroll
        for (int m = 0; m < 4; ++m) {
            int row0 = wm * 64 + m * 16 + fq * 4;
            f32x4 az = acc[m][p];
            f32x4 ah = acc[m][p + 2];
#pragma unroll
            for (int j = 0; j < 4; ++j) {
                float zt = 1.f / (1.f + __expf(-(az[j] + bz)));
                float e  = __expf(2.f * (ah[j] + bh));
                float s  = zt * (1.f - 2.f / (e + 1.f));
                plane[(row0 + j) * 68 + ucol] = s;
            }
        }
    }
    __syncthreads();

    // ---- transposed float4 stores: 256B contiguous per quarter-wave ----
    float* fwd = out;
    float* seq = out + (size_t)M_ROWS * 1024;
    const f32x4 z4 = (f32x4){0.f, 0.f, 0.f, 0.f};
    const int c4 = (tid & 15) * 4;
#pragma unroll
    for (int it = 0; it < 8; ++it) {
        int row = it * 16 + (tid >> 4);
        f32x4 v = *reinterpret_cast<const f32x4*>(&plane[row * 68 + c4]);
        size_t grow = (size_t)(brow + row);
        *reinterpret_cast<f32x4*>(&fwd[grow * 1024 + u0 + c4])       = v;
        *reinterpret_cast<f32x4*>(&fwd[grow * 1024 + 512 + u0 + c4]) = z4;
        *reinterpret_cast<f32x4*>(&seq[grow * 512 + u0 + c4])        = v;
    }
#undef ISSUE_AREG
#undef ISSUE_B
#undef CVT_WRITE_A
}

// ---------------------------------------------------------------------------
// Legacy fallback (round-1 kernel, needs no workspace) if ws is too small
// ---------------------------------------------------------------------------
#define LDSS 40
__global__ __launch_bounds__(256) void gru_fused_legacy(
    const float* __restrict__ inp, const float* __restrict__ w_z,
    const float* __restrict__ b_z, const float* __restrict__ w_h,
    const float* __restrict__ b_h, float* __restrict__ out)
{
    __shared__ __align__(16) unsigned short Asl[2][128][LDSS];
    __shared__ __align__(16) unsigned short Bsl[2][128][LDSS];
    const int tid = threadIdx.x, lane = tid & 63, wid = tid >> 6;
    const int wm = wid >> 1, wn = wid & 1;
    const int u0 = blockIdx.x * 64, brow = blockIdx.y * 128;
    f32x4 acc[4][4];
#pragma unroll
    for (int m = 0; m < 4; ++m)
#pragma unroll
        for (int n = 0; n < 4; ++n) acc[m][n] = (f32x4){0.f,0.f,0.f,0.f};
    f32x4 rA[4], rB[4];
#define STAGE_LOAD(kt) { const int k0_=(kt)*32; \
    _Pragma("unroll") for (int it=0; it<4; ++it){ int idx=tid+256*it; int r=idx>>3,c=(idx&7)<<2; \
        rA[it]=*reinterpret_cast<const f32x4*>(inp+(size_t)(brow+r)*IN_STRIDE+k0_+c);} \
    _Pragma("unroll") for (int it=0; it<4; ++it){ int idx=tid+256*it; int jj=idx&127; int k4=(idx>>7)<<2; \
        const float* w_=((jj>>5)&1)?w_h:w_z; int u_=u0+((jj>>6)<<5)+(jj&31); \
        const float* p_=w_+(size_t)(k0_+k4)*UDIM+u_; \
        rB[it][0]=p_[0]; rB[it][1]=p_[UDIM]; rB[it][2]=p_[2*UDIM]; rB[it][3]=p_[3*UDIM];} }
#define STAGE_WRITE(bufi) { \
    _Pragma("unroll") for (int it=0; it<4; ++it){ int idx=tid+256*it; int r=idx>>3,c=(idx&7)<<2; ushort4v v; \
        v[0]=f2bf(rA[it][0]); v[1]=f2bf(rA[it][1]); v[2]=f2bf(rA[it][2]); v[3]=f2bf(rA[it][3]); \
        *reinterpret_cast<ushort4v*>(&Asl[bufi][r][c])=v;} \
    _Pragma("unroll") for (int it=0; it<4; ++it){ int idx=tid+256*it; int jj=idx&127; int k4=(idx>>7)<<2; ushort4v v; \
        v[0]=f2bf(rB[it][0]); v[1]=f2bf(rB[it][1]); v[2]=f2bf(rB[it][2]); v[3]=f2bf(rB[it][3]); \
        *reinterpret_cast<ushort4v*>(&Bsl[bufi][jj][k4])=v;} }
    STAGE_LOAD(0); STAGE_WRITE(0);
    const int fr = lane & 15, koff = (lane >> 4) << 3;
    for (int kt = 0; kt < 16; ++kt) {
        if (kt + 1 < 16) STAGE_LOAD(kt + 1);
        __syncthreads();
        const int buf = kt & 1;
        short8 af[4], bfr[4];
#pragma unroll
        for (int m = 0; m < 4; ++m) af[m] = *reinterpret_cast<const short8*>(&Asl[buf][wm*64+m*16+fr][koff]);
#pragma unroll
        for (int n = 0; n < 4; ++n) bfr[n] = *reinterpret_cast<const short8*>(&Bsl[buf][wn*64+n*16+fr][koff]);
#pragma unroll
        for (int m = 0; m < 4; ++m)
#pragma unroll
            for (int n = 0; n < 4; ++n)
                acc[m][n] = __builtin_amdgcn_mfma_f32_16x16x32_bf16(af[m], bfr[n], acc[m][n], 0, 0, 0);
        if (kt + 1 < 16) STAGE_WRITE((kt + 1) & 1);
    }
    float* fwd = out; float* seq = out + (size_t)M_ROWS * 1024;
    const int fq = lane >> 4;
#pragma unroll
    for (int p = 0; p < 2; ++p) {
        int u = u0 + wn * 32 + p * 16 + fr;
        float bz = b_z[u], bh = b_h[u];
#pragma unroll
        for (int m = 0; m < 4; ++m) {
            int row0 = brow + wm * 64 + m * 16 + fq * 4;
            f32x4 az = acc[m][p], ah = acc[m][p + 2];
#pragma unroll
            for (int j = 0; j < 4; ++j) {
                float zt = 1.f / (1.f + __expf(-(az[j] + bz)));
                float e  = __expf(2.f * (ah[j] + bh));
                float s  = zt * (1.f - 2.f / (e + 1.f));
                size_t rr = (size_t)(row0 + j);
                fwd[rr * 1024 + u] = s;
                fwd[rr * 1024 + 512 + u] = 0.f;
                seq[rr * 512 + u] = s;
            }
        }
    }
}

extern "C" void kernel_launch(void* const* d_in, const int* in_sizes, int n_in,
                              void* d_out, int out_size, void* d_ws, size_t ws_size,
                              hipStream_t stream) {
    const float* inp = (const float*)d_in[0];
    const float* w_z = (const float*)d_in[2];
    const float* b_z = (const float*)d_in[4];
    const float* w_h = (const float*)d_in[8];
    const float* b_h = (const float*)d_in[10];
    float* out = (float*)d_out;

    const size_t needW = (size_t)8 * 16 * 512 * 16;   // 1 MiB packed weights
    if (ws_size >= needW) {
        unsigned short* Wp = (unsigned short*)d_ws;
        hipLaunchKernelGGL(pack_w, dim3(256), dim3(256), 0, stream, w_z, w_h, Wp);
        hipLaunchKernelGGL(gru_gemm, dim3(1024), dim3(256), 0, stream,
                           inp, Wp, b_z, b_h, out);
    } else {
        hipLaunchKernelGGL(gru_fused_legacy, dim3(8, 128), dim3(256), 0, stream,
                           inp, w_z, b_z, w_h, b_h, out);
    }
}

// Round 12
// 46.098 us; speedup vs baseline: 1.4019x; 1.0024x over previous
//
#include <hip/hip_runtime.h>
#include <hip/hip_bf16.h>

typedef __attribute__((ext_vector_type(4))) float f32x4;
typedef __attribute__((ext_vector_type(8))) short short8;
typedef __attribute__((ext_vector_type(8))) unsigned short ushort8;
typedef __attribute__((ext_vector_type(4))) unsigned short ushort4v;

#define M_ROWS 16384
#define KDIM 512
#define UDIM 512
#define IN_STRIDE 1024
#define NSTEP 16          // K / 32

__device__ __forceinline__ unsigned short f2bf(float f) {
    union { float f; unsigned u; } v; v.f = f;
    unsigned r = v.u + 0x7FFFu + ((v.u >> 16) & 1u);  // RTNE
    return (unsigned short)(r >> 16);
}

// packed RNE f32x2 -> bf16x2 (compiler emits v_cvt_pk_bf16_f32)
__device__ __forceinline__ unsigned cvt2(float a, float b) {
    __hip_bfloat162 h = __float22bfloat162_rn(float2{a, b});
    union { __hip_bfloat162 h; unsigned u; } c; c.h = h; return c.u;
}

// global_load_lds, width 16 (literal required)
#define GLD16(g, l)                                                            \
    __builtin_amdgcn_global_load_lds(                                          \
        (const __attribute__((address_space(1))) void*)(g),                    \
        (__attribute__((address_space(3))) void*)(l), 16, 0, 0)

// ---------------------------------------------------------------------------
// weights pack: Wp[ub 8][kt 16][s 512] x 16B slots, XOR-swizzle baked into
// the k-slot order so gru_gemm's global_load_lds consumes it linearly.
// ---------------------------------------------------------------------------
__global__ __launch_bounds__(256) void pack_w(
    const float* __restrict__ w_z,
    const float* __restrict__ w_h,
    unsigned short* __restrict__ Wp)
{
    int tid = blockIdx.x * 256 + threadIdx.x;   // [0, 65536)
    int s   = tid & 511;
    int kt  = (tid >> 9) & 15;
    int ub  = tid >> 13;
    int jj  = s >> 2;
    int sl  = (s & 3) ^ ((jj >> 1) & 3);
    int k   = kt * 32 + sl * 8;
    const float* w = ((jj >> 5) & 1) ? w_h : w_z;
    int u = ub * 64 + ((jj >> 6) << 5) + (jj & 31);
    ushort8 v;
#pragma unroll
    for (int i = 0; i < 8; ++i)
        v[i] = f2bf(w[(size_t)(k + i) * UDIM + u]);
    *reinterpret_cast<ushort8*>(Wp + (size_t)tid * 8) = v;
}

// ---------------------------------------------------------------------------
// Fused GEMM (R9 structure, residency 3 -> 4 blocks/CU): 128x128 tile, BK=32,
// 4 waves. A: x fp32 -> regs (depth-2 ring) -> v_cvt_pk_bf16_f32 ->
// ds_write_b128 into bf16 [128][32] tile (2 bufs). B: packed Wp via
// global_load_lds, ring-3. Counted vmcnt(6), asm-fenced barriers, per-wave
// lgkmcnt(0) drain. LDS 40960 B exactly -> 4 blocks = full 160 KiB/CU; grid
// 1024 = 4 x 256 CUs -> all blocks resident, barriers hidden by TLP.
// ---------------------------------------------------------------------------
__global__ __launch_bounds__(256, 4) void gru_gemm(
    const float* __restrict__ x,            // (16384, 1024), cols [0,512) used
    const unsigned short* __restrict__ Wp,  // packed weights
    const float* __restrict__ b_z,
    const float* __restrict__ b_h,
    float* __restrict__ out)
{
    __shared__ __align__(16) unsigned char smem[40960];
    unsigned short* shA = (unsigned short*)smem;            // 2 bufs x 4096 u16
    unsigned short* shB = (unsigned short*)(smem + 16384);  // 3 bufs x 4096 u16

    const int tid  = threadIdx.x;
    const int lane = tid & 63;
    const int wid  = tid >> 6;
    const int wm   = wid >> 1;
    const int wn   = wid & 1;

    // XCD-aware swizzle: the 8 u-blocks of a row-panel land on one XCD
    const int d  = blockIdx.x;               // [0,1024)
    const int bx = (d >> 3) & 7;             // u-block
    const int by = (d & 7) * 16 + (d >> 6);  // row-panel
    const int u0   = bx * 64;
    const int brow = by * 128;

    // ---- A staging: thread owns 2 16B LDS slots; slot s -> row r=s>>2,
    //      piece p=s&3; content = global k-octet q = p ^ ((r>>1)&3) ----
    const int s0a = wid * 128 + lane;
    const int s1a = s0a + 64;
    const int r0 = s0a >> 2, r1 = s1a >> 2;
    const int q0 = (s0a & 3) ^ ((r0 >> 1) & 3);
    const int q1 = (s1a & 3) ^ ((r1 >> 1) & 3);
    const float* gA0 = x + (size_t)(brow + r0) * IN_STRIDE + q0 * 8;
    const float* gA1 = x + (size_t)(brow + r1) * IN_STRIDE + q1 * 8;

    const unsigned short* bp = Wp + (size_t)bx * 65536 + (size_t)s0a * 8;

    f32x4 acc[4][4];
#pragma unroll
    for (int m = 0; m < 4; ++m)
#pragma unroll
        for (int n = 0; n < 4; ++n)
            acc[m][n] = (f32x4){0.f, 0.f, 0.f, 0.f};

    f32x4 rA[2][4];   // A in-flight register ring (static indices under unroll)

#define ISSUE_AREG(t, set)                                                     \
    {                                                                          \
        rA[set][0] = *reinterpret_cast<const f32x4*>(gA0 + (t) * 32);          \
        rA[set][1] = *reinterpret_cast<const f32x4*>(gA0 + (t) * 32 + 4);      \
        rA[set][2] = *reinterpret_cast<const f32x4*>(gA1 + (t) * 32);          \
        rA[set][3] = *reinterpret_cast<const f32x4*>(gA1 + (t) * 32 + 4);      \
    }

#define ISSUE_B(t, b)                                                          \
    {                                                                          \
        GLD16(bp + (size_t)(t) * 4096,       shB + (b) * 4096 + wid * 1024);   \
        GLD16(bp + (size_t)(t) * 4096 + 512, shB + (b) * 4096 + wid * 1024 + 512); \
    }

#define CVT_WRITE_A(set, b)                                                    \
    {                                                                          \
        union { unsigned u[4]; ushort8 v; } c0, c1;                            \
        c0.u[0] = cvt2(rA[set][0][0], rA[set][0][1]);                          \
        c0.u[1] = cvt2(rA[set][0][2], rA[set][0][3]);                          \
        c0.u[2] = cvt2(rA[set][1][0], rA[set][1][1]);                          \
        c0.u[3] = cvt2(rA[set][1][2], rA[set][1][3]);                          \
        c1.u[0] = cvt2(rA[set][2][0], rA[set][2][1]);                          \
        c1.u[1] = cvt2(rA[set][2][2], rA[set][2][3]);                          \
        c1.u[2] = cvt2(rA[set][3][0], rA[set][3][1]);                          \
        c1.u[3] = cvt2(rA[set][3][2], rA[set][3][3]);                          \
        *reinterpret_cast<ushort8*>(&shA[(b) * 4096 + s0a * 8]) = c0.v;        \
        *reinterpret_cast<ushort8*>(&shA[(b) * 4096 + s1a * 8]) = c1.v;        \
    }

    // fragment read offsets (ushort units), xo swizzle (R4-proven, both tiles)
    const int fr = lane & 15;
    const int ks = lane >> 4;
    const int xo = (fr >> 1) & 3;
    int aoff[4], boff[4];
#pragma unroll
    for (int m = 0; m < 4; ++m)
        aoff[m] = (wm * 64 + m * 16 + fr) * 32 + ((ks ^ xo) << 3);
#pragma unroll
    for (int n = 0; n < 4; ++n)
        boff[n] = (wn * 64 + n * 16 + fr) * 32 + ((ks ^ xo) << 3);

    // prologue: stages 0,1 in flight; land 0, write A(0), fenced barrier
    ISSUE_AREG(0, 0); ISSUE_B(0, 0);
    ISSUE_AREG(1, 1); ISSUE_B(1, 1);
    asm volatile("s_waitcnt vmcnt(6)" ::: "memory");   // A(0) regs + B(0) LDS
    CVT_WRITE_A(0, 0);
    asm volatile("s_waitcnt lgkmcnt(0)" ::: "memory");
    asm volatile("s_barrier" ::: "memory");

#pragma unroll
    for (int t = 0; t < NSTEP; ++t) {
        if (t + 2 < NSTEP) {
            ISSUE_AREG(t + 2, t & 1);        // set t&1 consumed at step t-1
            ISSUE_B(t + 2, (t + 2) % 3);     // slot read at t-1, waves past it
        }
        const int ba = t & 1, bb = t % 3;
        short8 af[4], bfrag[4];
#pragma unroll
        for (int m = 0; m < 4; ++m)
            af[m] = *reinterpret_cast<const short8*>(&shA[ba * 4096 + aoff[m]]);
#pragma unroll
        for (int n = 0; n < 4; ++n)
            bfrag[n] = *reinterpret_cast<const short8*>(&shB[bb * 4096 + boff[n]]);
#pragma unroll
        for (int m = 0; m < 4; ++m)
#pragma unroll
            for (int n = 0; n < 4; ++n)
                acc[m][n] = __builtin_amdgcn_mfma_f32_16x16x32_bf16(af[m], bfrag[n], acc[m][n], 0, 0, 0);
        if (t + 1 < NSTEP) {
            if (t + 2 < NSTEP) {
                // A(t+1) regs + B(t+1) LDS landed; stage t+2's 6 ops in flight
                asm volatile("s_waitcnt vmcnt(6)" ::: "memory");
            } else {
                asm volatile("s_waitcnt vmcnt(0)" ::: "memory");
            }
            CVT_WRITE_A((t + 1) & 1, (t + 1) & 1);  // buffer consumed at t-1
            // my frag reads + A-writes complete before crossing the barrier
            asm volatile("s_waitcnt lgkmcnt(0)" ::: "memory");
            asm volatile("s_barrier" ::: "memory");
        }
    }

    __syncthreads();   // full fence before LDS reuse (drains lgkm+vm per wave)

    // ---- epilogue: s = sigmoid(z+bz)*tanh(h+bh) in regs -> LDS plane ----
    float* plane = (float*)smem;   // [128][68] f32 = 34816 B, fits in 40960
    const int fq = lane >> 4;
#pragma unroll
    for (int p = 0; p < 2; ++p) {
        int ucol = wn * 32 + p * 16 + fr;
        float bz = b_z[u0 + ucol];
        float bh = b_h[u0 + ucol];
#pragma unroll
        for (int m = 0; m < 4; ++m) {
            int row0 = wm * 64 + m * 16 + fq * 4;
            f32x4 az = acc[m][p];
            f32x4 ah = acc[m][p + 2];
#pragma unroll
            for (int j = 0; j < 4; ++j) {
                float zt = 1.f / (1.f + __expf(-(az[j] + bz)));
                float e  = __expf(2.f * (ah[j] + bh));
                float s  = zt * (1.f - 2.f / (e + 1.f));
                plane[(row0 + j) * 68 + ucol] = s;
            }
        }
    }
    __syncthreads();

    // ---- transposed float4 stores: 256B contiguous per quarter-wave ----
    float* fwd = out;
    float* seq = out + (size_t)M_ROWS * 1024;
    const f32x4 z4 = (f32x4){0.f, 0.f, 0.f, 0.f};
    const int c4 = (tid & 15) * 4;
#pragma unroll
    for (int it = 0; it < 8; ++it) {
        int row = it * 16 + (tid >> 4);
        f32x4 v = *reinterpret_cast<const f32x4*>(&plane[row * 68 + c4]);
        size_t grow = (size_t)(brow + row);
        *reinterpret_cast<f32x4*>(&fwd[grow * 1024 + u0 + c4])       = v;
        *reinterpret_cast<f32x4*>(&fwd[grow * 1024 + 512 + u0 + c4]) = z4;
        *reinterpret_cast<f32x4*>(&seq[grow * 512 + u0 + c4])        = v;
    }
#undef ISSUE_AREG
#undef ISSUE_B
#undef CVT_WRITE_A
}

// ---------------------------------------------------------------------------
// Legacy fallback (round-1 kernel, needs no workspace) if ws is too small
// ---------------------------------------------------------------------------
#define LDSS 40
__global__ __launch_bounds__(256) void gru_fused_legacy(
    const float* __restrict__ inp, const float* __restrict__ w_z,
    const float* __restrict__ b_z, const float* __restrict__ w_h,
    const float* __restrict__ b_h, float* __restrict__ out)
{
    __shared__ __align__(16) unsigned short Asl[2][128][LDSS];
    __shared__ __align__(16) unsigned short Bsl[2][128][LDSS];
    const int tid = threadIdx.x, lane = tid & 63, wid = tid >> 6;
    const int wm = wid >> 1, wn = wid & 1;
    const int u0 = blockIdx.x * 64, brow = blockIdx.y * 128;
    f32x4 acc[4][4];
#pragma unroll
    for (int m = 0; m < 4; ++m)
#pragma unroll
        for (int n = 0; n < 4; ++n) acc[m][n] = (f32x4){0.f,0.f,0.f,0.f};
    f32x4 rA[4], rB[4];
#define STAGE_LOAD(kt) { const int k0_=(kt)*32; \
    _Pragma("unroll") for (int it=0; it<4; ++it){ int idx=tid+256*it; int r=idx>>3,c=(idx&7)<<2; \
        rA[it]=*reinterpret_cast<const f32x4*>(inp+(size_t)(brow+r)*IN_STRIDE+k0_+c);} \
    _Pragma("unroll") for (int it=0; it<4; ++it){ int idx=tid+256*it; int jj=idx&127; int k4=(idx>>7)<<2; \
        const float* w_=((jj>>5)&1)?w_h:w_z; int u_=u0+((jj>>6)<<5)+(jj&31); \
        const float* p_=w_+(size_t)(k0_+k4)*UDIM+u_; \
        rB[it][0]=p_[0]; rB[it][1]=p_[UDIM]; rB[it][2]=p_[2*UDIM]; rB[it][3]=p_[3*UDIM];} }
#define STAGE_WRITE(bufi) { \
    _Pragma("unroll") for (int it=0; it<4; ++it){ int idx=tid+256*it; int r=idx>>3,c=(idx&7)<<2; ushort4v v; \
        v[0]=f2bf(rA[it][0]); v[1]=f2bf(rA[it][1]); v[2]=f2bf(rA[it][2]); v[3]=f2bf(rA[it][3]); \
        *reinterpret_cast<ushort4v*>(&Asl[bufi][r][c])=v;} \
    _Pragma("unroll") for (int it=0; it<4; ++it){ int idx=tid+256*it; int jj=idx&127; int k4=(idx>>7)<<2; ushort4v v; \
        v[0]=f2bf(rB[it][0]); v[1]=f2bf(rB[it][1]); v[2]=f2bf(rB[it][2]); v[3]=f2bf(rB[it][3]); \
        *reinterpret_cast<ushort4v*>(&Bsl[bufi][jj][k4])=v;} }
    STAGE_LOAD(0); STAGE_WRITE(0);
    const int fr = lane & 15, koff = (lane >> 4) << 3;
    for (int kt = 0; kt < 16; ++kt) {
        if (kt + 1 < 16) STAGE_LOAD(kt + 1);
        __syncthreads();
        const int buf = kt & 1;
        short8 af[4], bfr[4];
#pragma unroll
        for (int m = 0; m < 4; ++m) af[m] = *reinterpret_cast<const short8*>(&Asl[buf][wm*64+m*16+fr][koff]);
#pragma unroll
        for (int n = 0; n < 4; ++n) bfr[n] = *reinterpret_cast<const short8*>(&Bsl[buf][wn*64+n*16+fr][koff]);
#pragma unroll
        for (int m = 0; m < 4; ++m)
#pragma unroll
            for (int n = 0; n < 4; ++n)
                acc[m][n] = __builtin_amdgcn_mfma_f32_16x16x32_bf16(af[m], bfr[n], acc[m][n], 0, 0, 0);
        if (kt + 1 < 16) STAGE_WRITE((kt + 1) & 1);
    }
    float* fwd = out; float* seq = out + (size_t)M_ROWS * 1024;
    const int fq = lane >> 4;
#pragma unroll
    for (int p = 0; p < 2; ++p) {
        int u = u0 + wn * 32 + p * 16 + fr;
        float bz = b_z[u], bh = b_h[u];
#pragma unroll
        for (int m = 0; m < 4; ++m) {
            int row0 = brow + wm * 64 + m * 16 + fq * 4;
            f32x4 az = acc[m][p], ah = acc[m][p + 2];
#pragma unroll
            for (int j = 0; j < 4; ++j) {
                float zt = 1.f / (1.f + __expf(-(az[j] + bz)));
                float e  = __expf(2.f * (ah[j] + bh));
                float s  = zt * (1.f - 2.f / (e + 1.f));
                size_t rr = (size_t)(row0 + j);
                fwd[rr * 1024 + u] = s;
                fwd[rr * 1024 + 512 + u] = 0.f;
                seq[rr * 512 + u] = s;
            }
        }
    }
}

extern "C" void kernel_launch(void* const* d_in, const int* in_sizes, int n_in,
                              void* d_out, int out_size, void* d_ws, size_t ws_size,
                              hipStream_t stream) {
    const float* inp = (const float*)d_in[0];
    const float* w_z = (const float*)d_in[2];
    const float* b_z = (const float*)d_in[4];
    const float* w_h = (const float*)d_in[8];
    const float* b_h = (const float*)d_in[10];
    float* out = (float*)d_out;

    const size_t needW = (size_t)8 * 16 * 512 * 16;   // 1 MiB packed weights
    if (ws_size >= needW) {
        unsigned short* Wp = (unsigned short*)d_ws;
        hipLaunchKernelGGL(pack_w, dim3(256), dim3(256), 0, stream, w_z, w_h, Wp);
        hipLaunchKernelGGL(gru_gemm, dim3(1024), dim3(256), 0, stream,
                           inp, Wp, b_z, b_h, out);
    } else {
        hipLaunchKernelGGL(gru_fused_legacy, dim3(8, 128), dim3(256), 0, stream,
                           inp, w_z, b_z, w_h, b_h, out);
    }
}

// Round 13
// 46.047 us; speedup vs baseline: 1.4035x; 1.0011x over previous
//
#include <hip/hip_runtime.h>
#include <hip/hip_bf16.h>

typedef __attribute__((ext_vector_type(4))) float f32x4;
typedef __attribute__((ext_vector_type(8))) short short8;
typedef __attribute__((ext_vector_type(8))) unsigned short ushort8;
typedef __attribute__((ext_vector_type(4))) unsigned short ushort4v;

#define M_ROWS 16384
#define KDIM 512
#define UDIM 512
#define IN_STRIDE 1024
#define NSTEP 16          // K / 32

__device__ __forceinline__ unsigned short f2bf(float f) {
    union { float f; unsigned u; } v; v.f = f;
    unsigned r = v.u + 0x7FFFu + ((v.u >> 16) & 1u);  // RTNE
    return (unsigned short)(r >> 16);
}

// packed RNE f32x2 -> bf16x2 (compiler emits v_cvt_pk_bf16_f32)
__device__ __forceinline__ unsigned cvt2(float a, float b) {
    __hip_bfloat162 h = __float22bfloat162_rn(float2{a, b});
    union { __hip_bfloat162 h; unsigned u; } c; c.h = h; return c.u;
}

// global_load_lds, width 16 (literal required)
#define GLD16(g, l)                                                            \
    __builtin_amdgcn_global_load_lds(                                          \
        (const __attribute__((address_space(1))) void*)(g),                    \
        (__attribute__((address_space(3))) void*)(l), 16, 0, 0)

// ---------------------------------------------------------------------------
// weights pack: Wp[ub 8][kt 16][s 512] x 16B slots, XOR-swizzle baked into
// the k-slot order so gru_gemm's global_load_lds consumes it linearly.
// ---------------------------------------------------------------------------
__global__ __launch_bounds__(256) void pack_w(
    const float* __restrict__ w_z,
    const float* __restrict__ w_h,
    unsigned short* __restrict__ Wp)
{
    int tid = blockIdx.x * 256 + threadIdx.x;   // [0, 65536)
    int s   = tid & 511;
    int kt  = (tid >> 9) & 15;
    int ub  = tid >> 13;
    int jj  = s >> 2;
    int sl  = (s & 3) ^ ((jj >> 1) & 3);
    int k   = kt * 32 + sl * 8;
    const float* w = ((jj >> 5) & 1) ? w_h : w_z;
    int u = ub * 64 + ((jj >> 6) << 5) + (jj & 31);
    ushort8 v;
#pragma unroll
    for (int i = 0; i < 8; ++i)
        v[i] = f2bf(w[(size_t)(k + i) * UDIM + u]);
    *reinterpret_cast<ushort8*>(Wp + (size_t)tid * 8) = v;
}

// ---------------------------------------------------------------------------
// Fused GEMM (R9 structure, residency 3 -> 4 blocks/CU): 128x128 tile, BK=32,
// 4 waves. A: x fp32 -> regs (depth-2 ring) -> v_cvt_pk_bf16_f32 ->
// ds_write_b128 into bf16 [128][32] tile (2 bufs). B: packed Wp via
// global_load_lds, ring-3. Counted vmcnt(6), asm-fenced barriers, per-wave
// lgkmcnt(0) drain. LDS 40960 B exactly -> 4 blocks = full 160 KiB/CU; grid
// 1024 = 4 x 256 CUs -> all blocks resident, barriers hidden by TLP.
// ---------------------------------------------------------------------------
__global__ __launch_bounds__(256, 4) void gru_gemm(
    const float* __restrict__ x,            // (16384, 1024), cols [0,512) used
    const unsigned short* __restrict__ Wp,  // packed weights
    const float* __restrict__ b_z,
    const float* __restrict__ b_h,
    float* __restrict__ out)
{
    __shared__ __align__(16) unsigned char smem[40960];
    unsigned short* shA = (unsigned short*)smem;            // 2 bufs x 4096 u16
    unsigned short* shB = (unsigned short*)(smem + 16384);  // 3 bufs x 4096 u16

    const int tid  = threadIdx.x;
    const int lane = tid & 63;
    const int wid  = tid >> 6;
    const int wm   = wid >> 1;
    const int wn   = wid & 1;

    // XCD-aware swizzle: the 8 u-blocks of a row-panel land on one XCD
    const int d  = blockIdx.x;               // [0,1024)
    const int bx = (d >> 3) & 7;             // u-block
    const int by = (d & 7) * 16 + (d >> 6);  // row-panel
    const int u0   = bx * 64;
    const int brow = by * 128;

    // ---- A staging: thread owns 2 16B LDS slots; slot s -> row r=s>>2,
    //      piece p=s&3; content = global k-octet q = p ^ ((r>>1)&3) ----
    const int s0a = wid * 128 + lane;
    const int s1a = s0a + 64;
    const int r0 = s0a >> 2, r1 = s1a >> 2;
    const int q0 = (s0a & 3) ^ ((r0 >> 1) & 3);
    const int q1 = (s1a & 3) ^ ((r1 >> 1) & 3);
    const float* gA0 = x + (size_t)(brow + r0) * IN_STRIDE + q0 * 8;
    const float* gA1 = x + (size_t)(brow + r1) * IN_STRIDE + q1 * 8;

    const unsigned short* bp = Wp + (size_t)bx * 65536 + (size_t)s0a * 8;

    f32x4 acc[4][4];
#pragma unroll
    for (int m = 0; m < 4; ++m)
#pragma unroll
        for (int n = 0; n < 4; ++n)
            acc[m][n] = (f32x4){0.f, 0.f, 0.f, 0.f};

    f32x4 rA[2][4];   // A in-flight register ring (static indices under unroll)

#define ISSUE_AREG(t, set)                                                     \
    {                                                                          \
        rA[set][0] = *reinterpret_cast<const f32x4*>(gA0 + (t) * 32);          \
        rA[set][1] = *reinterpret_cast<const f32x4*>(gA0 + (t) * 32 + 4);      \
        rA[set][2] = *reinterpret_cast<const f32x4*>(gA1 + (t) * 32);          \
        rA[set][3] = *reinterpret_cast<const f32x4*>(gA1 + (t) * 32 + 4);      \
    }

#define ISSUE_B(t, b)                                                          \
    {                                                                          \
        GLD16(bp + (size_t)(t) * 4096,       shB + (b) * 4096 + wid * 1024);   \
        GLD16(bp + (size_t)(t) * 4096 + 512, shB + (b) * 4096 + wid * 1024 + 512); \
    }

#define CVT_WRITE_A(set, b)                                                    \
    {                                                                          \
        union { unsigned u[4]; ushort8 v; } c0, c1;                            \
        c0.u[0] = cvt2(rA[set][0][0], rA[set][0][1]);                          \
        c0.u[1] = cvt2(rA[set][0][2], rA[set][0][3]);                          \
        c0.u[2] = cvt2(rA[set][1][0], rA[set][1][1]);                          \
        c0.u[3] = cvt2(rA[set][1][2], rA[set][1][3]);                          \
        c1.u[0] = cvt2(rA[set][2][0], rA[set][2][1]);                          \
        c1.u[1] = cvt2(rA[set][2][2], rA[set][2][3]);                          \
        c1.u[2] = cvt2(rA[set][3][0], rA[set][3][1]);                          \
        c1.u[3] = cvt2(rA[set][3][2], rA[set][3][3]);                          \
        *reinterpret_cast<ushort8*>(&shA[(b) * 4096 + s0a * 8]) = c0.v;        \
        *reinterpret_cast<ushort8*>(&shA[(b) * 4096 + s1a * 8]) = c1.v;        \
    }

    // fragment read offsets (ushort units), xo swizzle (R4-proven, both tiles)
    const int fr = lane & 15;
    const int ks = lane >> 4;
    const int xo = (fr >> 1) & 3;
    int aoff[4], boff[4];
#pragma unroll
    for (int m = 0; m < 4; ++m)
        aoff[m] = (wm * 64 + m * 16 + fr) * 32 + ((ks ^ xo) << 3);
#pragma unroll
    for (int n = 0; n < 4; ++n)
        boff[n] = (wn * 64 + n * 16 + fr) * 32 + ((ks ^ xo) << 3);

    // prologue: stages 0,1 in flight; land 0, write A(0), fenced barrier
    ISSUE_AREG(0, 0); ISSUE_B(0, 0);
    ISSUE_AREG(1, 1); ISSUE_B(1, 1);
    asm volatile("s_waitcnt vmcnt(6)" ::: "memory");   // A(0) regs + B(0) LDS
    CVT_WRITE_A(0, 0);
    asm volatile("s_waitcnt lgkmcnt(0)" ::: "memory");
    asm volatile("s_barrier" ::: "memory");

#pragma unroll
    for (int t = 0; t < NSTEP; ++t) {
        if (t + 2 < NSTEP) {
            ISSUE_AREG(t + 2, t & 1);        // set t&1 consumed at step t-1
            ISSUE_B(t + 2, (t + 2) % 3);     // slot read at t-1, waves past it
        }
        const int ba = t & 1, bb = t % 3;
        short8 af[4], bfrag[4];
#pragma unroll
        for (int m = 0; m < 4; ++m)
            af[m] = *reinterpret_cast<const short8*>(&shA[ba * 4096 + aoff[m]]);
#pragma unroll
        for (int n = 0; n < 4; ++n)
            bfrag[n] = *reinterpret_cast<const short8*>(&shB[bb * 4096 + boff[n]]);
#pragma unroll
        for (int m = 0; m < 4; ++m)
#pragma unroll
            for (int n = 0; n < 4; ++n)
                acc[m][n] = __builtin_amdgcn_mfma_f32_16x16x32_bf16(af[m], bfrag[n], acc[m][n], 0, 0, 0);
        if (t + 1 < NSTEP) {
            if (t + 2 < NSTEP) {
                // A(t+1) regs + B(t+1) LDS landed; stage t+2's 6 ops in flight
                asm volatile("s_waitcnt vmcnt(6)" ::: "memory");
            } else {
                asm volatile("s_waitcnt vmcnt(0)" ::: "memory");
            }
            CVT_WRITE_A((t + 1) & 1, (t + 1) & 1);  // buffer consumed at t-1
            // my frag reads + A-writes complete before crossing the barrier
            asm volatile("s_waitcnt lgkmcnt(0)" ::: "memory");
            asm volatile("s_barrier" ::: "memory");
        }
    }

    __syncthreads();   // full fence before LDS reuse (drains lgkm+vm per wave)

    // ---- epilogue: s = sigmoid(z+bz)*tanh(h+bh) in regs -> LDS plane ----
    float* plane = (float*)smem;   // [128][68] f32 = 34816 B, fits in 40960
    const int fq = lane >> 4;
#pragma unroll
    for (int p = 0; p < 2; ++p) {
        int ucol = wn * 32 + p * 16 + fr;
        float bz = b_z[u0 + ucol];
        float bh = b_h[u0 + ucol];
#pragma unroll
        for (int m = 0; m < 4; ++m) {
            int row0 = wm * 64 + m * 16 + fq * 4;
            f32x4 az = acc[m][p];
            f32x4 ah = acc[m][p + 2];
#pragma unroll
            for (int j = 0; j < 4; ++j) {
                float zt = 1.f / (1.f + __expf(-(az[j] + bz)));
                float e  = __expf(2.f * (ah[j] + bh));
                float s  = zt * (1.f - 2.f / (e + 1.f));
                plane[(row0 + j) * 68 + ucol] = s;
            }
        }
    }
    __syncthreads();

    // ---- transposed float4 stores: 256B contiguous per quarter-wave ----
    float* fwd = out;
    float* seq = out + (size_t)M_ROWS * 1024;
    const f32x4 z4 = (f32x4){0.f, 0.f, 0.f, 0.f};
    const int c4 = (tid & 15) * 4;
#pragma unroll
    for (int it = 0; it < 8; ++it) {
        int row = it * 16 + (tid >> 4);
        f32x4 v = *reinterpret_cast<const f32x4*>(&plane[row * 68 + c4]);
        size_t grow = (size_t)(brow + row);
        *reinterpret_cast<f32x4*>(&fwd[grow * 1024 + u0 + c4])       = v;
        *reinterpret_cast<f32x4*>(&fwd[grow * 1024 + 512 + u0 + c4]) = z4;
        *reinterpret_cast<f32x4*>(&seq[grow * 512 + u0 + c4])        = v;
    }
#undef ISSUE_AREG
#undef ISSUE_B
#undef CVT_WRITE_A
}

// ---------------------------------------------------------------------------
// Legacy fallback (round-1 kernel, needs no workspace) if ws is too small
// ---------------------------------------------------------------------------
#define LDSS 40
__global__ __launch_bounds__(256) void gru_fused_legacy(
    const float* __restrict__ inp, const float* __restrict__ w_z,
    const float* __restrict__ b_z, const float* __restrict__ w_h,
    const float* __restrict__ b_h, float* __restrict__ out)
{
    __shared__ __align__(16) unsigned short Asl[2][128][LDSS];
    __shared__ __align__(16) unsigned short Bsl[2][128][LDSS];
    const int tid = threadIdx.x, lane = tid & 63, wid = tid >> 6;
    const int wm = wid >> 1, wn = wid & 1;
    const int u0 = blockIdx.x * 64, brow = blockIdx.y * 128;
    f32x4 acc[4][4];
#pragma unroll
    for (int m = 0; m < 4; ++m)
#pragma unroll
        for (int n = 0; n < 4; ++n) acc[m][n] = (f32x4){0.f,0.f,0.f,0.f};
    f32x4 rA[4], rB[4];
#define STAGE_LOAD(kt) { const int k0_=(kt)*32; \
    _Pragma("unroll") for (int it=0; it<4; ++it){ int idx=tid+256*it; int r=idx>>3,c=(idx&7)<<2; \
        rA[it]=*reinterpret_cast<const f32x4*>(inp+(size_t)(brow+r)*IN_STRIDE+k0_+c);} \
    _Pragma("unroll") for (int it=0; it<4; ++it){ int idx=tid+256*it; int jj=idx&127; int k4=(idx>>7)<<2; \
        const float* w_=((jj>>5)&1)?w_h:w_z; int u_=u0+((jj>>6)<<5)+(jj&31); \
        const float* p_=w_+(size_t)(k0_+k4)*UDIM+u_; \
        rB[it][0]=p_[0]; rB[it][1]=p_[UDIM]; rB[it][2]=p_[2*UDIM]; rB[it][3]=p_[3*UDIM];} }
#define STAGE_WRITE(bufi) { \
    _Pragma("unroll") for (int it=0; it<4; ++it){ int idx=tid+256*it; int r=idx>>3,c=(idx&7)<<2; ushort4v v; \
        v[0]=f2bf(rA[it][0]); v[1]=f2bf(rA[it][1]); v[2]=f2bf(rA[it][2]); v[3]=f2bf(rA[it][3]); \
        *reinterpret_cast<ushort4v*>(&Asl[bufi][r][c])=v;} \
    _Pragma("unroll") for (int it=0; it<4; ++it){ int idx=tid+256*it; int jj=idx&127; int k4=(idx>>7)<<2; ushort4v v; \
        v[0]=f2bf(rB[it][0]); v[1]=f2bf(rB[it][1]); v[2]=f2bf(rB[it][2]); v[3]=f2bf(rB[it][3]); \
        *reinterpret_cast<ushort4v*>(&Bsl[bufi][jj][k4])=v;} }
    STAGE_LOAD(0); STAGE_WRITE(0);
    const int fr = lane & 15, koff = (lane >> 4) << 3;
    for (int kt = 0; kt < 16; ++kt) {
        if (kt + 1 < 16) STAGE_LOAD(kt + 1);
        __syncthreads();
        const int buf = kt & 1;
        short8 af[4], bfr[4];
#pragma unroll
        for (int m = 0; m < 4; ++m) af[m] = *reinterpret_cast<const short8*>(&Asl[buf][wm*64+m*16+fr][koff]);
#pragma unroll
        for (int n = 0; n < 4; ++n) bfr[n] = *reinterpret_cast<const short8*>(&Bsl[buf][wn*64+n*16+fr][koff]);
#pragma unroll
        for (int m = 0; m < 4; ++m)
#pragma unroll
            for (int n = 0; n < 4; ++n)
                acc[m][n] = __builtin_amdgcn_mfma_f32_16x16x32_bf16(af[m], bfr[n], acc[m][n], 0, 0, 0);
        if (kt + 1 < 16) STAGE_WRITE((kt + 1) & 1);
    }
    float* fwd = out; float* seq = out + (size_t)M_ROWS * 1024;
    const int fq = lane >> 4;
#pragma unroll
    for (int p = 0; p < 2; ++p) {
        int u = u0 + wn * 32 + p * 16 + fr;
        float bz = b_z[u], bh = b_h[u];
#pragma unroll
        for (int m = 0; m < 4; ++m) {
            int row0 = brow + wm * 64 + m * 16 + fq * 4;
            f32x4 az = acc[m][p], ah = acc[m][p + 2];
#pragma unroll
            for (int j = 0; j < 4; ++j) {
                float zt = 1.f / (1.f + __expf(-(az[j] + bz)));
                float e  = __expf(2.f * (ah[j] + bh));
                float s  = zt * (1.f - 2.f / (e + 1.f));
                size_t rr = (size_t)(row0 + j);
                fwd[rr * 1024 + u] = s;
                fwd[rr * 1024 + 512 + u] = 0.f;
                seq[rr * 512 + u] = s;
            }
        }
    }
}

extern "C" void kernel_launch(void* const* d_in, const int* in_sizes, int n_in,
                              void* d_out, int out_size, void* d_ws, size_t ws_size,
                              hipStream_t stream) {
    const float* inp = (const float*)d_in[0];
    const float* w_z = (const float*)d_in[2];
    const float* b_z = (const float*)d_in[4];
    const float* w_h = (const float*)d_in[8];
    const float* b_h = (const float*)d_in[10];
    float* out = (float*)d_out;

    const size_t needW = (size_t)8 * 16 * 512 * 16;   // 1 MiB packed weights
    if (ws_size >= needW) {
        unsigned short* Wp = (unsigned short*)d_ws;
        hipLaunchKernelGGL(pack_w, dim3(256), dim3(256), 0, stream, w_z, w_h, Wp);
        hipLaunchKernelGGL(gru_gemm, dim3(1024), dim3(256), 0, stream,
                           inp, Wp, b_z, b_h, out);
    } else {
        hipLaunchKernelGGL(gru_fused_legacy, dim3(8, 128), dim3(256), 0, stream,
                           inp, w_z, b_z, w_h, b_h, out);
    }
}